// Round 1
// baseline (301.793 us; speedup 1.0000x reference)
//
#include <hip/hip_runtime.h>
#include <math.h>

// Problem constants (from reference): B=256, T=2048, I=128, H=128
#define BB 256
#define TT 2048
#define II 128
#define HH 128
#define GG 512                      // 4*H gates
#define SLOT_FLOATS (TT * GG)       // per-active-batch x_proj slot: 4 MiB
#define TC 16                       // x staging chunk (timesteps) for fallback path

__device__ __forceinline__ float sigmoidf_(float v) {
    return 1.0f / (1.0f + expf(-v));
}

// ---------------------------------------------------------------------------
// Phase A: precompute x_proj = x @ W_ih^T + b_ih + b_hh for active batches
// (lengths[b] == T) that fit in a workspace slot. Grid: (B, T/64), 512 thr.
// ---------------------------------------------------------------------------
__global__ __launch_bounds__(GG, 2) void xproj_kernel(
    const float* __restrict__ x, const int* __restrict__ lengths,
    const float* __restrict__ W_ih, const float* __restrict__ b_ih,
    const float* __restrict__ b_hh, float* __restrict__ ws, int slots)
{
    const int b = blockIdx.x;
    if (lengths[b] != TT) return;                 // inactive batch: nothing to do
    int rank = 0;
    for (int k = 0; k < b; ++k) rank += (lengths[k] == TT);
    if (rank >= slots) return;                    // no slot; Phase B falls back

    const int g  = threadIdx.x;                   // gate index 0..511
    const int t0 = blockIdx.y * 64;

    __shared__ float xs[64][II];                  // 32 KiB x tile
    const float4* xin = (const float4*)(x + ((size_t)b * TT + t0) * II);
    float4* xs4 = (float4*)&xs[0][0];
    for (int idx = g; idx < 64 * II / 4; idx += GG) xs4[idx] = xin[idx];
    __syncthreads();

    // W_ih row for this gate in registers (128 floats)
    float4 wr[32];
    const float4* wrow = (const float4*)(W_ih + (size_t)g * II);
#pragma unroll
    for (int i = 0; i < 32; ++i) wr[i] = wrow[i];

    const float bias = b_ih[g] + b_hh[g];
    float* outp = ws + (size_t)rank * SLOT_FLOATS + (size_t)t0 * GG + g;

    for (int t = 0; t < 64; ++t) {
        float acc = bias;
        const float4* xr = (const float4*)&xs[t][0];
#pragma unroll
        for (int i = 0; i < 32; ++i) {
            float4 xv = xr[i];                    // broadcast LDS read
            acc += wr[i].x * xv.x + wr[i].y * xv.y + wr[i].z * xv.z + wr[i].w * xv.w;
        }
        outp[(size_t)t * GG] = acc;               // coalesced across g
    }
}

// ---------------------------------------------------------------------------
// Phase B: sequential LSTM recurrence, one block per batch.
// Inactive batches (lengths[b] != T) write zeros (pad_packed zero-pads them).
// ---------------------------------------------------------------------------
__global__ __launch_bounds__(GG, 2) void lstm_kernel(
    const float* __restrict__ x, const int* __restrict__ lengths,
    const float* __restrict__ W_ih, const float* __restrict__ W_hh,
    const float* __restrict__ b_ih, const float* __restrict__ b_hh,
    const float* __restrict__ ws, int slots, float* __restrict__ out)
{
    const int b = blockIdx.x;
    const int g = threadIdx.x;                    // gate index 0..511
    const int len = lengths[b];
    if (len != TT) {
        if (g < HH) out[b * HH + g] = 0.0f;       // exact zero rows
        return;
    }

    int rank = 0;
    for (int k = 0; k < b; ++k) rank += (lengths[k] == TT);
    const bool use_ws = (rank < slots);           // block-uniform

    __shared__ float h_lds[HH];
    __shared__ float gates_lds[GG];
    __shared__ float xs[TC][II];                  // only used in fallback path

    // W_hh row for this gate in registers (128 floats = 128 VGPRs)
    float4 wh[32];
    const float4* whrow = (const float4*)(W_hh + (size_t)g * HH);
#pragma unroll
    for (int i = 0; i < 32; ++i) wh[i] = whrow[i];

    const float4* wirow = (const float4*)(W_ih + (size_t)g * II);
    const float bias = b_ih[g] + b_hh[g];
    const float* xp_base = ws + (size_t)rank * SLOT_FLOATS + g;

    float c = 0.0f;
    if (g < HH) h_lds[g] = 0.0f;
    __syncthreads();

    for (int t = 0; t < TT; ++t) {
        float acc;
        if (use_ws) {
            acc = xp_base[(size_t)t * GG];        // coalesced, bias included
        } else {
            if ((t & (TC - 1)) == 0) {            // stage next x chunk
                const float4* xin = (const float4*)(x + ((size_t)b * TT + t) * II);
                float4* xs4 = (float4*)&xs[0][0];
                for (int idx = g; idx < TC * II / 4; idx += GG) xs4[idx] = xin[idx];
                __syncthreads();
            }
            acc = bias;
            const float4* xr = (const float4*)&xs[t & (TC - 1)][0];
#pragma unroll
            for (int i = 0; i < 32; ++i) {
                float4 wv = wirow[i];             // streamed from L2 each step
                float4 xv = xr[i];
                acc += wv.x * xv.x + wv.y * xv.y + wv.z * xv.z + wv.w * xv.w;
            }
        }

        // recurrent part: acc += W_hh[g] . h
        const float4* hr = (const float4*)&h_lds[0];
#pragma unroll
        for (int i = 0; i < 32; ++i) {
            float4 hv = hr[i];                    // broadcast LDS read
            acc += wh[i].x * hv.x + wh[i].y * hv.y + wh[i].z * hv.z + wh[i].w * hv.w;
        }
        gates_lds[g] = acc;
        __syncthreads();

        if (g < HH) {                             // cell update (PyTorch order i,f,g,o)
            float iv = sigmoidf_(gates_lds[g]);
            float fv = sigmoidf_(gates_lds[HH + g]);
            float gv = tanhf(gates_lds[2 * HH + g]);
            float ov = sigmoidf_(gates_lds[3 * HH + g]);
            c = fv * c + iv * gv;
            h_lds[g] = ov * tanhf(c);
        }
        __syncthreads();
    }

    if (g < HH) out[b * HH + g] = h_lds[g];
}

// ---------------------------------------------------------------------------
extern "C" void kernel_launch(void* const* d_in, const int* in_sizes, int n_in,
                              void* d_out, int out_size, void* d_ws, size_t ws_size,
                              hipStream_t stream) {
    const float* x       = (const float*)d_in[0];
    const int*   lengths = (const int*)d_in[1];
    const float* W_ih    = (const float*)d_in[2];
    const float* W_hh    = (const float*)d_in[3];
    const float* b_ih    = (const float*)d_in[4];
    const float* b_hh    = (const float*)d_in[5];
    float* out = (float*)d_out;
    float* ws  = (float*)d_ws;

    const size_t slot_bytes = (size_t)SLOT_FLOATS * sizeof(float);
    int slots = (int)(ws_size / slot_bytes);
    if (slots > 8) slots = 8;                     // >8 full-length batches is ~impossible

    if (slots > 0) {
        hipLaunchKernelGGL(xproj_kernel, dim3(BB, TT / 64), dim3(GG), 0, stream,
                           x, lengths, W_ih, b_ih, b_hh, ws, slots);
    }
    hipLaunchKernelGGL(lstm_kernel, dim3(BB), dim3(GG), 0, stream,
                       x, lengths, W_ih, W_hh, b_ih, b_hh, ws, slots, out);
}

// Round 2
// 296.503 us; speedup vs baseline: 1.0178x; 1.0178x over previous
//
#include <hip/hip_runtime.h>
#include <math.h>

// Problem constants (from reference): B=256, T=2048, I=128, H=128
#define BB 256
#define TT 2048
#define II 128
#define HH 128
#define GG 512                      // 4*H gates
#define SLOT_FLOATS (TT * GG)       // per-batch x_proj slot: 4 MiB (ws = 1 GiB = 256 slots)
#define TC 16                       // x staging chunk (timesteps)

__device__ __forceinline__ float sigmoidf_(float v) {
    return 1.0f / (1.0f + expf(-v));
}

// One block per batch. Inactive batches (lengths[b] != T) contribute exact
// zeros per the reference's pad_packed semantics — write and exit.
// Active batches: Phase 1 computes x_proj into the ws slot (W_ih rows in
// VGPRs), Phase 2 runs the serial recurrence (W_hh rows in VGPRs). The two
// 128-VGPR weight sets are never live simultaneously, keeping the kernel
// under the 256-VGPR cap needed for 2 waves/SIMD (8-wave block).
__global__ __launch_bounds__(GG, 2) void lstm_fused(
    const float* __restrict__ x, const int* __restrict__ lengths,
    const float* __restrict__ W_ih, const float* __restrict__ W_hh,
    const float* __restrict__ b_ih, const float* __restrict__ b_hh,
    float* __restrict__ ws, int slots, float* __restrict__ out)
{
    const int b = blockIdx.x;
    const int g = threadIdx.x;                    // gate index 0..511

    if (lengths[b] != TT) {                       // block-uniform early exit
        if (g < HH) out[b * HH + g] = 0.0f;
        return;
    }

    const bool use_ws = (b < slots);              // block-uniform
    __shared__ float xs[TC][II];                  // 8 KiB x staging tile
    __shared__ float h_lds[HH];
    __shared__ float gates_lds[GG];

    const float bias = b_ih[g] + b_hh[g];
    const float4* wirow = (const float4*)(W_ih + (size_t)g * II);

    // ---------------- Phase 1: x_proj[t][g] -> ws slot b ----------------
    if (use_ws) {
        float4 wi[32];                            // W_ih row: 128 VGPRs
#pragma unroll
        for (int i = 0; i < 32; ++i) wi[i] = wirow[i];

        float* xp_out = ws + (size_t)b * SLOT_FLOATS + g;
        for (int t0 = 0; t0 < TT; t0 += TC) {
            __syncthreads();                      // xs reuse guard
            const float4* xin = (const float4*)(x + ((size_t)b * TT + t0) * II);
            ((float4*)&xs[0][0])[g] = xin[g];     // TC*II/4 == GG exactly
            __syncthreads();
#pragma unroll 4
            for (int tt = 0; tt < TC; ++tt) {
                float dot = 0.0f;
                const float4* xr = (const float4*)&xs[tt][0];
#pragma unroll
                for (int i = 0; i < 32; ++i) {
                    float4 xv = xr[i];            // broadcast LDS read
                    dot += wi[i].x * xv.x + wi[i].y * xv.y
                         + wi[i].z * xv.z + wi[i].w * xv.w;
                }
                xp_out[(size_t)(t0 + tt) * GG] = bias + dot;  // coalesced in g
            }
        }
    }

    // ---------------- Phase 2: serial recurrence ----------------
    float4 wh[32];                                // W_hh row: 128 VGPRs
    const float4* whrow = (const float4*)(W_hh + (size_t)g * HH);
#pragma unroll
    for (int i = 0; i < 32; ++i) wh[i] = whrow[i];

    const float* xp_in = ws + (size_t)b * SLOT_FLOATS + g;

    float c = 0.0f;
    if (g < HH) h_lds[g] = 0.0f;
    __syncthreads();

    for (int t = 0; t < TT; ++t) {
        float acc;
        if (use_ws) {
            // Issue the (latency ~L2) slot read first; consume after the
            // h-dot so the 64+ VALU instructions hide it.
            float xp = xp_in[(size_t)t * GG];     // coalesced, bias included
            float dot = 0.0f;
            const float4* hr = (const float4*)&h_lds[0];
#pragma unroll
            for (int i = 0; i < 32; ++i) {
                float4 hv = hr[i];                // broadcast LDS read
                dot += wh[i].x * hv.x + wh[i].y * hv.y
                     + wh[i].z * hv.z + wh[i].w * hv.w;
            }
            acc = xp + dot;
        } else {
            // Correctness-only fallback (ws too small): stream W_ih from L2.
            if ((t & (TC - 1)) == 0) {
                __syncthreads();
                const float4* xin = (const float4*)(x + ((size_t)b * TT + t) * II);
                ((float4*)&xs[0][0])[g] = xin[g];
                __syncthreads();
            }
            acc = bias;
            const float4* xr = (const float4*)&xs[t & (TC - 1)][0];
            for (int i = 0; i < 32; ++i) {
                float4 wv = wirow[i];
                float4 xv = xr[i];
                acc += wv.x * xv.x + wv.y * xv.y + wv.z * xv.z + wv.w * xv.w;
            }
            const float4* hr = (const float4*)&h_lds[0];
#pragma unroll
            for (int i = 0; i < 32; ++i) {
                float4 hv = hr[i];
                acc += wh[i].x * hv.x + wh[i].y * hv.y
                     + wh[i].z * hv.z + wh[i].w * hv.w;
            }
        }

        gates_lds[g] = acc;
        __syncthreads();                          // h reads done + gates visible

        if (g < HH) {                             // cell update (i, f, g, o)
            float iv = sigmoidf_(gates_lds[g]);
            float fv = sigmoidf_(gates_lds[HH + g]);
            float gv = tanhf(gates_lds[2 * HH + g]);
            float ov = sigmoidf_(gates_lds[3 * HH + g]);
            c = fv * c + iv * gv;
            h_lds[g] = ov * tanhf(c);
        }
        __syncthreads();                          // new h visible to all
    }

    if (g < HH) out[b * HH + g] = h_lds[g];
}

// ---------------------------------------------------------------------------
extern "C" void kernel_launch(void* const* d_in, const int* in_sizes, int n_in,
                              void* d_out, int out_size, void* d_ws, size_t ws_size,
                              hipStream_t stream) {
    const float* x       = (const float*)d_in[0];
    const int*   lengths = (const int*)d_in[1];
    const float* W_ih    = (const float*)d_in[2];
    const float* W_hh    = (const float*)d_in[3];
    const float* b_ih    = (const float*)d_in[4];
    const float* b_hh    = (const float*)d_in[5];
    float* out = (float*)d_out;
    float* ws  = (float*)d_ws;

    int slots = (int)(ws_size / ((size_t)SLOT_FLOATS * sizeof(float)));
    if (slots > BB) slots = BB;

    hipLaunchKernelGGL(lstm_fused, dim3(BB), dim3(GG), 0, stream,
                       x, lengths, W_ih, W_hh, b_ih, b_hh, ws, slots, out);
}